// Round 4
// baseline (266.409 us; speedup 1.0000x reference)
//
#include <hip/hip_runtime.h>
#include <hip/hip_bf16.h>

#define NN 100000
#define BB 64
#define EE 1600000
#define FD 128
#define SLOTC 64                  // slot capacity per graph (keep<=9 + ties mathematically)
#define KSLOTS (BB * SLOTC)       // 4096 total slot space
#define EMAX (1 << 18)
#define LCAP 12288                // LDS logit cache (graphs avg ~1562 nodes)

// monotone float<->uint encoding for atomicMax; 0u decodes below any finite float
__device__ __forceinline__ unsigned encf(float f) {
    unsigned u = __float_as_uint(f);
    return (u & 0x80000000u) ? ~u : (u | 0x80000000u);
}
__device__ __forceinline__ float decf(unsigned u) {
    return __uint_as_float((u & 0x80000000u) ? (u & 0x7FFFFFFFu) : ~u);
}

// K1: one block per graph. bidx is sorted -> contiguous node range per graph.
// Fuses: logit, per-graph softmax (max/sum/max-score), keep decision, slot
// allocation (region-based, counter-free), h0/deg/ps init, kf zeroing, kecnt=0.
__global__ __launch_bounds__(256) void k_scorekeep(
    const float* __restrict__ x, const int* __restrict__ bidx,
    const float* __restrict__ tw,
    unsigned char* __restrict__ kf, int* __restrict__ nslot,
    int* __restrict__ knt, float* __restrict__ degs,
    float* __restrict__ h0s, float* __restrict__ ps, int* __restrict__ kecnt)
{
    __shared__ float cache[LCAP];
    __shared__ float red[256];
    __shared__ int   klist[SLOTC];
    __shared__ int   lcnt;
    __shared__ float bm, bs, bthr;
    int b = blockIdx.x, tid = threadIdx.x;
    if (tid == 0) { lcnt = 0; if (b == 0) *kecnt = 0; }

    // binary searches (all threads do identical searches -> broadcast loads)
    int lo = 0, hi = NN;
    while (lo < hi) { int mid = (lo + hi) >> 1; if (bidx[mid] < b) lo = mid + 1; else hi = mid; }
    int s0 = lo;
    hi = NN;
    while (lo < hi) { int mid = (lo + hi) >> 1; if (bidx[mid] < b + 1) lo = mid + 1; else hi = mid; }
    int L = lo - s0;
    float w0 = tw[0], w1 = tw[1];
    bool fit = (L <= LCAP);
    __syncthreads();

    // pass 1: logits + block max; zero kf for whole range
    float mx = -3.4028235e38f;
    for (int j = tid; j < L; j += 256) {
        int i = s0 + j;
        float l = x[2 * i] * w0 + x[2 * i + 1] * w1;
        if (fit) cache[j] = l;
        kf[i] = 0;
        mx = fmaxf(mx, l);
    }
    red[tid] = mx; __syncthreads();
    for (int s = 128; s > 0; s >>= 1) { if (tid < s) red[tid] = fmaxf(red[tid], red[tid + s]); __syncthreads(); }
    if (tid == 0) bm = red[0];
    __syncthreads();
    float m = bm;

    // pass 2: sum of exp
    float sm = 0.f;
    for (int j = tid; j < L; j += 256) {
        float l = fit ? cache[j] : (x[2 * (s0 + j)] * w0 + x[2 * (s0 + j) + 1] * w1);
        float e = expf(l - m);
        if (fit) cache[j] = e;
        sm += e;
    }
    red[tid] = sm; __syncthreads();
    for (int s = 128; s > 0; s >>= 1) { if (tid < s) red[tid] += red[tid + s]; __syncthreads(); }
    if (tid == 0) bs = red[0];
    __syncthreads();
    float S = bs;

    // pass 3: scores + max score
    float smx = -3.4028235e38f;
    for (int j = tid; j < L; j += 256) {
        float e = fit ? cache[j] : expf(x[2 * (s0 + j)] * w0 + x[2 * (s0 + j) + 1] * w1 - m);
        float sc = e / S;
        if (fit) cache[j] = sc;
        smx = fmaxf(smx, sc);
    }
    red[tid] = smx; __syncthreads();
    for (int s = 128; s > 0; s >>= 1) { if (tid < s) red[tid] = fmaxf(red[tid], red[tid + s]); __syncthreads(); }
    if (tid == 0) bthr = fminf(red[0] - 1e-7f, 0.1f);
    __syncthreads();
    float thr = bthr;

    // pass 4: claim keeps into block-local list
    for (int j = tid; j < L; j += 256) {
        float sc = fit ? cache[j] : expf(x[2 * (s0 + j)] * w0 + x[2 * (s0 + j) + 1] * w1 - m) / S;
        if (sc > thr) {
            int l = atomicAdd(&lcnt, 1);
            if (l < SLOTC) klist[l] = j;
        }
    }
    __syncthreads();
    int cnt = lcnt; if (cnt > SLOTC) cnt = SLOTC;
    if (tid == 0) knt[b] = cnt;
    for (int l = tid; l < cnt; l += 256) {
        int j = klist[l], i = s0 + j;
        float sc = fit ? cache[j] : expf(x[2 * i] * w0 + x[2 * i + 1] * w1 - m) / S;
        int slot = b * SLOTC + l;
        kf[i] = 1; nslot[i] = slot;
        degs[slot] = 1.0f;                     // self-loop
        h0s[2 * slot]     = x[2 * i] * sc;
        h0s[2 * slot + 1] = x[2 * i + 1] * sc;
        ps[2 * slot] = 0.f; ps[2 * slot + 1] = 0.f;
    }
}

// K2: full edge scan; keep kept-kept edges (as slot pairs), accumulate degree.
__global__ void k_edges(const int* __restrict__ ei, const unsigned char* __restrict__ kf,
                        const int* __restrict__ nslot, float* __restrict__ degs,
                        int* __restrict__ kedge, int* __restrict__ kecnt) {
    int e = blockIdx.x * 256 + threadIdx.x;
    if (e >= EE) return;
    int s = ei[e], d = ei[EE + e];
    if ((kf[s] & kf[d]) != 0) {
        int ds = nslot[d];
        atomicAdd(&degs[ds], 1.0f);
        int idx = atomicAdd(kecnt, 1);
        if (idx < EMAX) { kedge[2 * idx] = nslot[s]; kedge[2 * idx + 1] = ds; }
    }
}

// K3: single block; everything after the edge scan (work is ~kc*128, kc~64).
// __syncthreads() replaces 10 kernel boundaries.
__global__ __launch_bounds__(1024) void k_tail(
    float* __restrict__ degs, const float* __restrict__ h0s, float* __restrict__ ps,
    const int* __restrict__ kedge, const int* __restrict__ kecnt,
    const int* __restrict__ knt,
    const float* __restrict__ W1, const float* __restrict__ b1,
    const float* __restrict__ g1, const float* __restrict__ be1,
    const float* __restrict__ rm1, const float* __restrict__ rv1,
    const float* __restrict__ W2, const float* __restrict__ b2,
    const float* __restrict__ g2, const float* __restrict__ be2,
    const float* __restrict__ rm2, const float* __restrict__ rv2,
    const float* __restrict__ W3, const float* __restrict__ b3,
    const float* __restrict__ g3, const float* __restrict__ be3,
    const float* __restrict__ rm3, const float* __restrict__ rv3,
    const float* __restrict__ linW, const float* __restrict__ linb,
    float* __restrict__ hA, float* __restrict__ hB, float* __restrict__ out)
{
    __shared__ int slist[KSLOTS];        // 16 KB: compact -> slot
    __shared__ int cmap[KSLOTS];         // 16 KB: slot -> compact
    __shared__ unsigned pooled[BB * FD]; // 32 KB: encoded max-pool
    __shared__ int kcS;
    int tid = threadIdx.x;
    if (tid == 0) {
        int off = 0;
        for (int b = 0; b < BB; b++) {
            int c = knt[b];
            for (int l = 0; l < c; l++) { int slot = b * SLOTC + l; slist[off] = slot; cmap[slot] = off; off++; }
        }
        kcS = off;
    }
    for (int j = tid; j < BB * FD; j += 1024) pooled[j] = 0u;
    __syncthreads();
    int kc = kcS;
    int ke = *kecnt; if (ke > EMAX) ke = EMAX;

    // dinv
    for (int j = tid; j < kc; j += 1024) { int s = slist[j]; degs[s] = rsqrtf(degs[s]); }
    __syncthreads();
    // layer-1 edge agg on 2-wide raw features
    for (int idx = tid; idx < ke; idx += 1024) {
        int s = kedge[2 * idx], d = kedge[2 * idx + 1];
        float nm = degs[s] * degs[d];
        atomicAdd(&ps[2 * d],     nm * h0s[2 * s]);
        atomicAdd(&ps[2 * d + 1], nm * h0s[2 * s + 1]);
    }
    __syncthreads();
    // layer-1 node -> hA (compact row-major)
    for (int j = tid; j < kc * FD; j += 1024) {
        int r = j >> 7, f = j & 127, slot = slist[r];
        float di = degs[slot], d2 = di * di;
        float a0 = ps[2 * slot]     + d2 * h0s[2 * slot];
        float a1 = ps[2 * slot + 1] + d2 * h0s[2 * slot + 1];
        float v = a0 * W1[f] + a1 * W1[FD + f] + b1[f];
        v = fmaxf(v, 0.f);
        v = (v - rm1[f]) * rsqrtf(rv1[f] + 1e-5f) * g1[f] + be1[f];
        hA[j] = v;
    }
    __syncthreads();

    float* X = hA; float* Y = hB;
    const float* Wl[2]  = {W2, W3};  const float* bl[2]  = {b2, b3};
    const float* gl[2]  = {g2, g3};  const float* bel[2] = {be2, be3};
    const float* rml[2] = {rm2, rm3}; const float* rvl[2] = {rv2, rv3};
    for (int layer = 0; layer < 2; layer++) {
        const float* W = Wl[layer];
        // mm: Y = X @ W   (128 threads share a row -> broadcast X, coalesced W)
        for (int j = tid; j < kc * FD; j += 1024) {
            int r = j >> 7, f = j & 127;
            const float* xr = X + r * FD;
            float acc = 0.f;
            #pragma unroll 8
            for (int k = 0; k < FD; k++) acc += xr[k] * W[k * FD + f];
            Y[j] = acc;
        }
        __syncthreads();
        for (int j = tid; j < kc * FD; j += 1024) X[j] = 0.f;   // X becomes agg
        __syncthreads();
        for (int idx = tid; idx < ke * FD; idx += 1024) {
            int e = idx >> 7, f = idx & 127;
            int s = kedge[2 * e], d = kedge[2 * e + 1];
            float nm = degs[s] * degs[d];
            atomicAdd(&X[cmap[d] * FD + f], nm * Y[cmap[s] * FD + f]);
        }
        __syncthreads();
        // bn into Y
        for (int j = tid; j < kc * FD; j += 1024) {
            int r = j >> 7, f = j & 127, slot = slist[r];
            float di = degs[slot];
            float v = X[j] + di * di * Y[j] + bl[layer][f];
            v = fmaxf(v, 0.f);
            v = (v - rml[layer][f]) * rsqrtf(rvl[layer][f] + 1e-5f) * gl[layer][f] + bel[layer][f];
            Y[j] = v;
        }
        __syncthreads();
        float* t = X; X = Y; Y = t;
    }
    // pool (final features are in X)
    for (int j = tid; j < kc * FD; j += 1024) {
        int r = j >> 7, f = j & 127, slot = slist[r], b = slot / SLOTC;
        atomicMax(&pooled[b * FD + f], encf(X[j]));
    }
    __syncthreads();
    // linear + log_softmax
    if (tid < BB) {
        int b = tid;
        float z0 = linb[0], z1 = linb[1], z2 = linb[2];
        for (int f = 0; f < FD; f++) {
            unsigned u = pooled[b * FD + f];
            float pv = (u == 0u) ? -3.4028235e38f : decf(u);
            z0 += pv * linW[f * 3 + 0];
            z1 += pv * linW[f * 3 + 1];
            z2 += pv * linW[f * 3 + 2];
        }
        float m = fmaxf(z0, fmaxf(z1, z2));
        float l = m + logf(expf(z0 - m) + expf(z1 - m) + expf(z2 - m));
        out[b * 3 + 0] = z0 - l;
        out[b * 3 + 1] = z1 - l;
        out[b * 3 + 2] = z2 - l;
    }
}

extern "C" void kernel_launch(void* const* d_in, const int* in_sizes, int n_in,
                              void* d_out, int out_size, void* d_ws, size_t ws_size,
                              hipStream_t stream) {
    (void)in_sizes; (void)n_in; (void)out_size; (void)ws_size;
    const float* x    = (const float*)d_in[0];
    const int*   ei   = (const int*)d_in[1];
    const int*   bidx = (const int*)d_in[2];
    const float* tw   = (const float*)d_in[3];
    const float* W1 = (const float*)d_in[4],  *b1 = (const float*)d_in[5],  *g1 = (const float*)d_in[6];
    const float* be1= (const float*)d_in[7],  *rm1= (const float*)d_in[8],  *rv1= (const float*)d_in[9];
    const float* W2 = (const float*)d_in[10], *b2 = (const float*)d_in[11], *g2 = (const float*)d_in[12];
    const float* be2= (const float*)d_in[13], *rm2= (const float*)d_in[14], *rv2= (const float*)d_in[15];
    const float* W3 = (const float*)d_in[16], *b3 = (const float*)d_in[17], *g3 = (const float*)d_in[18];
    const float* be3= (const float*)d_in[19], *rm3= (const float*)d_in[20], *rv3= (const float*)d_in[21];
    const float* linW = (const float*)d_in[22], *linb = (const float*)d_in[23];
    float* out = (float*)d_out;

    char* w = (char*)d_ws;
    auto take = [&](size_t bytes) { char* r = w; w += (bytes + 255) & ~(size_t)255; return r; };
    unsigned char* kf = (unsigned char*)take(NN);
    int*   nslot = (int*)take((size_t)NN * 4);
    int*   knt   = (int*)take((size_t)BB * 4);
    int*   kecnt = (int*)take(16);
    float* degs  = (float*)take((size_t)KSLOTS * 4);
    float* h0s   = (float*)take((size_t)KSLOTS * 8);
    float* ps    = (float*)take((size_t)KSLOTS * 8);
    int*   kedge = (int*)take((size_t)EMAX * 8);
    float* hA    = (float*)take((size_t)KSLOTS * FD * 4);
    float* hB    = (float*)take((size_t)KSLOTS * FD * 4);

    k_scorekeep<<<BB, 256, 0, stream>>>(x, bidx, tw, kf, nslot, knt, degs, h0s, ps, kecnt);
    k_edges<<<(EE + 255) / 256, 256, 0, stream>>>(ei, kf, nslot, degs, kedge, kecnt);
    k_tail<<<1, 1024, 0, stream>>>(degs, h0s, ps, kedge, kecnt, knt,
                                   W1, b1, g1, be1, rm1, rv1,
                                   W2, b2, g2, be2, rm2, rv2,
                                   W3, b3, g3, be3, rm3, rv3,
                                   linW, linb, hA, hB, out);
}